// Round 12
// baseline (1347.547 us; speedup 1.0000x reference)
//
#include <hip/hip_runtime.h>
#include <math.h>

// Problem constants (B, L, D, H from the reference)
constexpr int Bsz = 4;
constexpr int Lsz = 2048;
constexpr int Dsz = 1024;
constexpr int Hn  = 8;
constexpr int Dh  = 128;   // Dsz / Hn
constexpr int GM  = Bsz * Lsz;   // 8192
constexpr int GK  = Dsz;         // 1024 (K dim of every projection GEMM)
constexpr int NT  = GK / 32;     // 32 K-tiles of BK=32

typedef __attribute__((ext_vector_type(8))) short bf16x8;
typedef __attribute__((ext_vector_type(4))) float f32x4;

union FragU { unsigned int u[4]; bf16x8 f; };

// async global->LDS, 16B per lane (wave-uniform base + lane*16 dest)
__device__ __forceinline__ void gload16(const void* g, void* l) {
    __builtin_amdgcn_global_load_lds(
        (const __attribute__((address_space(1))) unsigned int*)g,
        (__attribute__((address_space(3))) unsigned int*)l, 16, 0, 0);
}

// split two fp32 into packed bf16 hi-pair / lo-pair (hi=truncate, lo=residual)
__device__ __forceinline__ void split2(float f0, float f1,
                                       unsigned int& hp, unsigned int& lp) {
    unsigned int u0 = __float_as_uint(f0), u1 = __float_as_uint(f1);
    hp = (u0 >> 16) | (u1 & 0xffff0000u);
    float l0 = f0 - __uint_as_float(u0 & 0xffff0000u);
    float l1 = f1 - __uint_as_float(u1 & 0xffff0000u);
    lp = (__float_as_uint(l0) >> 16) | (__float_as_uint(l1) & 0xffff0000u);
}

__device__ __forceinline__ void split4(float4 f, ushort4& h, ushort4& l2) {
    unsigned int ux = __float_as_uint(f.x), uy = __float_as_uint(f.y),
                 uz = __float_as_uint(f.z), uw = __float_as_uint(f.w);
    h.x = (unsigned short)(ux >> 16); h.y = (unsigned short)(uy >> 16);
    h.z = (unsigned short)(uz >> 16); h.w = (unsigned short)(uw >> 16);
    float lx = f.x - __uint_as_float(ux & 0xffff0000u);
    float ly = f.y - __uint_as_float(uy & 0xffff0000u);
    float lz = f.z - __uint_as_float(uz & 0xffff0000u);
    float lw = f.w - __uint_as_float(uw & 0xffff0000u);
    l2.x = (unsigned short)(__float_as_uint(lx) >> 16);
    l2.y = (unsigned short)(__float_as_uint(ly) >> 16);
    l2.z = (unsigned short)(__float_as_uint(lz) >> 16);
    l2.w = (unsigned short)(__float_as_uint(lw) >> 16);
}

struct WConv4 {
    const float4* w[4];
    ushort4* h[4];
    ushort4* l[4];
    float s[4];
};

// 4 weights in one launch: 1024 blocks per weight (WD/4/256 = 1024)
__global__ __launch_bounds__(256) void conv_w4(WConv4 a) {
    int wi = blockIdx.x >> 10;
    int i = (blockIdx.x & 1023) * 256 + threadIdx.x;
    float4 f = a.w[wi][i];
    float s = a.s[wi];
    f.x *= s; f.y *= s; f.z *= s; f.w *= s;
    ushort4 h, l;
    split4(f, h, l);
    a.h[wi][i] = h; a.l[wi][i] = l;
}

// ---------------------------------------------------------------------------
// Shared compute core for the GEMMs:
// per wave (8 waves = 4M x 2N): 2 fm x 4 fn frags of 16x16x32 MFMA,
// 3-product split-bf16 accumulation (hi*hi + hi*lo + lo*hi).
// la = lane index into the A region (XOR-swizzled for gemm_qkv, plain l for
// gemm_o). B reads use plain l. 0 read bank conflicts either way (r3-meas).
// ---------------------------------------------------------------------------
__device__ __forceinline__ void compute_tile(const ushort* Ah, const ushort* Al,
                                             const ushort* Bh, const ushort* Bl,
                                             int wm, int wn, int l, int la,
                                             f32x4 acc[2][4]) {
    bf16x8 bh[4], bl4[4], ah[2], al[2];
#pragma unroll
    for (int fn = 0; fn < 4; ++fn) {
        int fng = wn * 4 + fn;
        bh[fn]  = *(const bf16x8*)&Bh[(fng * 64 + l) * 8];
        bl4[fn] = *(const bf16x8*)&Bl[(fng * 64 + l) * 8];
    }
#pragma unroll
    for (int fm = 0; fm < 2; ++fm) {
        int fmg = wm * 2 + fm;
        ah[fm] = *(const bf16x8*)&Ah[(fmg * 64 + la) * 8];
        al[fm] = *(const bf16x8*)&Al[(fmg * 64 + la) * 8];
    }
    __builtin_amdgcn_s_setprio(1);
#pragma unroll
    for (int fm = 0; fm < 2; ++fm)
#pragma unroll
        for (int fn = 0; fn < 4; ++fn) {
            acc[fm][fn] = __builtin_amdgcn_mfma_f32_16x16x32_bf16(
                ah[fm], bh[fn], acc[fm][fn], 0, 0, 0);
            acc[fm][fn] = __builtin_amdgcn_mfma_f32_16x16x32_bf16(
                ah[fm], bl4[fn], acc[fm][fn], 0, 0, 0);
            acc[fm][fn] = __builtin_amdgcn_mfma_f32_16x16x32_bf16(
                al[fm], bh[fn], acc[fm][fn], 0, 0, 0);
        }
    __builtin_amdgcn_s_setprio(0);
}

// split 8 consecutive fp32 (two float4) -> hi/lo bf16x8, store 16B each
__device__ __forceinline__ void split_write(ushort* Ah, ushort* Al, int aw,
                                            float4 v0, float4 v1) {
    uint4 h4, l4;
    split2(v0.x, v0.y, h4.x, l4.x);
    split2(v0.z, v0.w, h4.y, l4.y);
    split2(v1.x, v1.y, h4.z, l4.z);
    split2(v1.z, v1.w, h4.w, l4.w);
    *(uint4*)&Ah[aw] = h4;
    *(uint4*)&Al[aw] = l4;
}

// ---------------------------------------------------------------------------
// Fused QKV projection GEMM. N = 3072 over fused weights [Wq*s; Wk; Wv].
// v12: SINGLE-BUFFER, 4 BLOCKS/CU. r11 counters: qkv at 609 TF raw = the
// measured 2-phase structural ceiling for 128^2 dbuf at 2 blocks/CU
// (Occupancy 33%). Flash taught (r7/r8/r10, this workload): single-buffer
// + more co-resident blocks beats dbuf + fewer — inter-block TLP (m114)
// hides staging better than intra-block prefetch. LDS 64->32 KB; threads
// cap occupancy at 4 blocks/CU (2048 thr); launch_bounds(512,8) pins
// VGPR<=64 (r11 compiled at exactly 64 with MORE live state).
// Loop: stage B(t) gload + split_write A(t) -> sync -> issue A(t+1) reg
// loads (land under compute) -> compute(t) -> sync.
// A-layout XOR-swizzle kept (r9: conflicts 1.0e7 -> 0). Numerics identical.
// Outputs: cols [0,1024)->Qhi/Qlo; [1024,2048)->Khi/Klo row-major;
// [2048,3072)->Vthi/Vtlo TRANSPOSED. Row-tiles fully >= slen skip entirely.
// ---------------------------------------------------------------------------
__global__ __launch_bounds__(512, 8) void gemm_qkv(
    const float* __restrict__ Aq, const float* __restrict__ Ak,
    const ushort* __restrict__ Wfh, const ushort* __restrict__ Wfl,
    ushort* __restrict__ Qhi, ushort* __restrict__ Qlo,
    ushort* __restrict__ Khi, ushort* __restrict__ Klo,
    ushort* __restrict__ Vthi, ushort* __restrict__ Vtlo,
    const int* __restrict__ slen)
{
    const int tid = threadIdx.x;
    const int bm = blockIdx.y << 7;
    const int bn = blockIdx.x << 7;        // 0..2944 (fused N = 3072)
    const int grp = bn >> 10;              // 0:Q 1:K 2:V

    const int nk = slen[bm >> 11];
    if ((bm & (Lsz - 1)) >= nk) return;    // skipped tile, never read downstream

    // [region][128*32]; 0=A_hi 1=A_lo 2=B_hi 3=B_lo -> 32 KB single buffer
    __shared__ __align__(16) ushort lds[4][128 * 32];

    const float* A = (grp == 0) ? Aq : Ak;
    const int w  = tid >> 6;
    const int l  = tid & 63;
    const int wm = w >> 1;                 // 0..3 (M)
    const int wn = w & 1;                  // 0..1 (N)
    const int la = l ^ ((l >> 4) << 1);    // swizzled A frag-read lane index

    // A staging: thread owns row arow, 8 consecutive k at k-group kg
    // (32B/thread, 4 threads per 128B row -> full coalescing).
    const int arow = tid >> 2;
    const int kg   = tid & 3;
    const float* ag = A + (size_t)(bm + arow) * GK + (kg << 3);
    const int aw = ((((arow >> 4) << 6) + (kg << 4) + ((arow & 15) ^ (kg << 1))) << 3);

    // B staging: 512 threads x one 16B chunk each of hi and lo per K-tile
    const int brow = ((tid >> 6) << 4) + (tid & 15);
    const int bkk  = ((tid >> 4) & 3) << 3;
    const ushort* bgh = Wfh + (size_t)(bn + brow) * GK + bkk;
    const ushort* bgl = Wfl + (size_t)(bn + brow) * GK + bkk;

    f32x4 acc[2][4];
#pragma unroll
    for (int i = 0; i < 2; ++i)
#pragma unroll
        for (int j = 0; j < 4; ++j) acc[i][j] = (f32x4)0.f;

    // ---- prologue: A(0) -> regs -------------------------------------------
    float4 c0 = *(const float4*)(ag);
    float4 c1 = *(const float4*)(ag + 4);

    for (int t = 0; t < NT; ++t) {
        // stage tile t: B via gload_lds, A via reg+split ds_write
        gload16(bgh + t * 32, &lds[2][tid * 8]);
        gload16(bgl + t * 32, &lds[3][tid * 8]);
        split_write(&lds[0][0], &lds[1][0], aw, c0, c1);
        __syncthreads();                   // tile t fully staged (vmcnt+lgkm)
        if (t + 1 < NT) {                  // A(t+1) -> regs; lands under compute
            c0 = *(const float4*)(ag + (t + 1) * 32);
            c1 = *(const float4*)(ag + (t + 1) * 32 + 4);
        }
        compute_tile(&lds[0][0], &lds[1][0], &lds[2][0], &lds[3][0],
                     wm, wn, l, la, acc);
        __syncthreads();                   // all reads done before next stage
    }

    // epilogue: C/D layout row=(l>>4)*4+reg, col=l&15 (m89-verified)
    const int rq = (l >> 4) << 2;
    const int cq = l & 15;
    ushort* OH = (grp == 0) ? Qhi : Khi;   // grp 2 handled below
    ushort* OL = (grp == 0) ? Qlo : Klo;
#pragma unroll
    for (int fm = 0; fm < 2; ++fm) {
        int r0 = bm + wm * 32 + fm * 16 + rq;
#pragma unroll
        for (int fn = 0; fn < 4; ++fn) {
            int cn = (bn & 1023) + wn * 64 + fn * 16 + cq;
            if (grp < 2) {   // Q or K: row-major hi/lo
#pragma unroll
                for (int r = 0; r < 4; ++r) {
                    float f = acc[fm][fn][r];
                    unsigned int u = __float_as_uint(f);
                    float res = f - __uint_as_float(u & 0xffff0000u);
                    OH[(size_t)(r0 + r) * Dsz + cn] = (unsigned short)(u >> 16);
                    OL[(size_t)(r0 + r) * Dsz + cn] =
                        (unsigned short)(__float_as_uint(res) >> 16);
                }
            } else {         // V: transposed hi/lo
                ushort4 h4, l4;
                unsigned short* hp = (unsigned short*)&h4;
                unsigned short* lp = (unsigned short*)&l4;
#pragma unroll
                for (int r = 0; r < 4; ++r) {
                    float f = acc[fm][fn][r];
                    unsigned int u = __float_as_uint(f);
                    float res = f - __uint_as_float(u & 0xffff0000u);
                    hp[r] = (unsigned short)(u >> 16);
                    lp[r] = (unsigned short)(__float_as_uint(res) >> 16);
                }
                *(ushort4*)&Vthi[(size_t)cn * GM + r0] = h4;
                *(ushort4*)&Vtlo[(size_t)cn * GM + r0] = l4;
            }
        }
    }
}

// ---------------------------------------------------------------------------
// O-projection GEMM: out = O @ Wo^T, fp32 result. A pre-split (flash epilogue).
// ROUND-2 v3 unchanged: 2-phase (STAGE(t+1) -> compute(t) -> sync), all four
// operand tiles via global_load_lds (linear LDS, 0 conflicts), 512 thr,
// 64 KB LDS. Skipped row-tiles write zeros.
// ---------------------------------------------------------------------------
__global__ __launch_bounds__(512, 2) void gemm_o(
    const ushort* __restrict__ Ahi, const ushort* __restrict__ Alo,
    const ushort* __restrict__ Bhi, const ushort* __restrict__ Blo,
    float* __restrict__ C, const int* __restrict__ slen)
{
    const int tid = threadIdx.x;
    const int bm = blockIdx.y << 7;
    const int bn = blockIdx.x << 7;

    const int nk = slen[bm >> 11];
    if ((bm & (Lsz - 1)) >= nk) {
        int row = tid >> 2;
        int cb  = (tid & 3) << 5;          // 4 col-chunks of 32 floats
        float4 z = make_float4(0.f, 0.f, 0.f, 0.f);
        float4* cp = (float4*)(C + (size_t)(bm + row) * Dsz + bn + cb);
#pragma unroll
        for (int i = 0; i < 8; ++i) cp[i] = z;
        return;
    }

    __shared__ __align__(16) ushort lds[2][4][128 * 32];

    const int w  = tid >> 6;
    const int l  = tid & 63;
    const int wm = w >> 1;
    const int wn = w & 1;

    const int srow = ((tid >> 6) << 4) + (tid & 15);
    const int skk  = ((tid >> 4) & 3) << 3;
    const ushort* agh = Ahi + (size_t)(bm + srow) * GK + skk;
    const ushort* agl = Alo + (size_t)(bm + srow) * GK + skk;
    const ushort* bgh = Bhi + (size_t)(bn + srow) * GK + skk;
    const ushort* bgl = Blo + (size_t)(bn + srow) * GK + skk;

    f32x4 acc[2][4];
#pragma unroll
    for (int i = 0; i < 2; ++i)
#pragma unroll
        for (int j = 0; j < 4; ++j) acc[i][j] = (f32x4)0.f;

    // prologue: stage tile 0 -> buf0, drain, barrier
    gload16(agh, &lds[0][0][tid * 8]);
    gload16(agl, &lds[0][1][tid * 8]);
    gload16(bgh, &lds[0][2][tid * 8]);
    gload16(bgl, &lds[0][3][tid * 8]);
    __syncthreads();

    for (int t = 0; t < NT - 1; ++t) {
        const int p = t & 1;
        const int q = p ^ 1;
        gload16(agh + (t + 1) * 32, &lds[q][0][tid * 8]);
        gload16(agl + (t + 1) * 32, &lds[q][1][tid * 8]);
        gload16(bgh + (t + 1) * 32, &lds[q][2][tid * 8]);
        gload16(bgl + (t + 1) * 32, &lds[q][3][tid * 8]);
        compute_tile(&lds[p][0][0], &lds[p][1][0], &lds[p][2][0], &lds[p][3][0],
                     wm, wn, l, l, acc);
        __syncthreads();
    }
    {
        const int p = (NT - 1) & 1;
        compute_tile(&lds[p][0][0], &lds[p][1][0], &lds[p][2][0], &lds[p][3][0],
                     wm, wn, l, l, acc);
    }

    const int rq = (l >> 4) << 2;
    const int cq = l & 15;
#pragma unroll
    for (int fm = 0; fm < 2; ++fm) {
        int r0 = bm + wm * 32 + fm * 16 + rq;
#pragma unroll
        for (int fn = 0; fn < 4; ++fn) {
            int c0 = bn + wn * 64 + fn * 16 + cq;
#pragma unroll
            for (int r = 0; r < 4; ++r)
                C[(size_t)(r0 + r) * Dsz + c0] = acc[fm][fn][r];
        }
    }
}

// ---------------------------------------------------------------------------
// MFMA flash attention, split-bf16, max-free online softmax.
// r11-MEASURED BEST (unchanged): BQ=64 (256 thr = 4 waves, 16 q-rows per
// wave), BK=32, SINGLE-buffered 41 KB LDS, gload_lds -> __syncthreads,
// T5 s_setprio(1/0) around the QK and PV MFMA clusters.
// LDS lesson (r5 T14, r10 dbuf both regressed): flash's latency hiding comes
// from INTER-BLOCK TLP (3 blocks/CU at 41 KB); any intra-block overlap that
// grows LDS to 73 KB cuts capacity to 2 and loses more than it gains.
// BQ sweep measured: 128 -> 160us, 64 -> ~125us (best), 32 -> 162us.
// SKIP LOGIC: gemm_o zero-skips at 128-row granularity, so a 64-tile whose
// parent 128-tile is live but whose own q0 >= nk must WRITE ZEROS.
// O written pre-split in-place over Qhi/Qlo.
// ---------------------------------------------------------------------------
__global__ __launch_bounds__(256) void flash_mfma(
    const ushort* __restrict__ Qhi, const ushort* __restrict__ Qlo,
    const ushort* __restrict__ Khi, const ushort* __restrict__ Klo,
    const ushort* __restrict__ Vthi, const ushort* __restrict__ Vtlo,
    const int* __restrict__ slen,
    ushort* __restrict__ Ohi, ushort* __restrict__ Olo)
{
    __shared__ __align__(16) ushort Ks[32 * 256];           // 16 KB
    __shared__ __align__(16) ushort Vs[128 * 64];           // 16 KB
    __shared__ __align__(16) unsigned int Pb[4 * 16 * 36];  // 9 KB

    const int tid = threadIdx.x;
    const int w = tid >> 6, l = tid & 63;
    const int lg = l >> 4, lc = l & 15;
    const int q0 = blockIdx.x << 6;        // 64-row q-tile
    const int h = blockIdx.y, b = blockIdx.z;
    const int nk = slen[b];

    if ((q0 & ~127) >= nk) return;         // parent 128-tile skipped by gemm_o

    if (q0 >= nk) {
        // parent tile live but this half fully masked: write zeros so gemm_o
        // never reads stale Q rows.
#pragma unroll
        for (int rr = 0; rr < 4; ++rr) {
            int q = q0 + (w << 4) + (lg << 2) + rr;
            size_t base = (size_t)(b * Lsz + q) * Dsz + h * Dh + lc;
#pragma unroll
            for (int fd = 0; fd < 8; ++fd) {
                Ohi[base + fd * 16] = 0;
                Olo[base + fd * 16] = 0;
            }
        }
        return;
    }

    // ---- Q strip -> A-frags (pre-split bf16), once per block ----
    bf16x8 qh[4], ql[4];
    {
        size_t base = (size_t)(b * Lsz + q0 + (w << 4) + lc) * Dsz + h * Dh + lg * 8;
#pragma unroll
        for (int s = 0; s < 4; ++s) {
            qh[s] = *(const bf16x8*)&Qhi[base + s * 32];
            ql[s] = *(const bf16x8*)&Qlo[base + s * 32];
        }
    }

    // ---- staging decode (256 threads, 1024 chunks each of K and Vt) ----
    const ushort* ksrc[4]; int klds[4];
    const ushort* vsrc[4]; int vlds[4];
#pragma unroll
    for (int i = 0; i < 4; ++i) {
        int s = i * 256 + tid;              // K chunk: row j (32ch: 16 hi + 16 lo)
        int j = s >> 5, p = s & 31;
        int lg4 = (p & 15) ^ (j & 15);
        const ushort* base = (p & 16) ? Klo : Khi;
        ksrc[i] = base + (size_t)(b * Lsz + j) * Dsz + h * Dh + lg4 * 8;
        klds[i] = s * 8;
    }
#pragma unroll
    for (int i = 0; i < 4; ++i) {
        int s = i * 256 + tid;              // Vt chunk: row d (8ch: 4 hi + 4 lo)
        int d = s >> 3, p = s & 7;
        int lgc = p ^ (d & 7);
        const ushort* base = (lgc & 4) ? Vtlo : Vthi;
        vsrc[i] = base + (size_t)(h * Dh + d) * (Bsz * Lsz) + b * Lsz + (lgc & 3) * 8;
        vlds[i] = s * 8;
    }

    f32x4 oacc[8];
#pragma unroll
    for (int fd = 0; fd < 8; ++fd) oacc[fd] = (f32x4)0.f;
    float lsum[4] = {0.f, 0.f, 0.f, 0.f};
    const int pbase = w * (16 * 36);

    for (int kb = 0; kb < nk; kb += 32) {
        // ---- stage K + V^T tiles ----
#pragma unroll
        for (int i = 0; i < 4; ++i) gload16(ksrc[i] + (size_t)kb * Dsz, &Ks[klds[i]]);
#pragma unroll
        for (int i = 0; i < 4; ++i) gload16(vsrc[i] + kb, &Vs[vlds[i]]);
        __syncthreads();

        // ---- S = Q K^T (16x32 per wave) ----
        f32x4 sa[2] = {(f32x4)0.f, (f32x4)0.f};
        __builtin_amdgcn_s_setprio(1);
#pragma unroll
        for (int fn = 0; fn < 2; ++fn) {
            int j = fn * 16 + lc;
            int ro = j * 256;
#pragma unroll
            for (int s = 0; s < 4; ++s) {
                int phys = (s * 4 + lg) ^ (j & 15);
                bf16x8 kh = *(const bf16x8*)&Ks[ro + phys * 8];
                bf16x8 kl = *(const bf16x8*)&Ks[ro + 128 + phys * 8];
                sa[fn] = __builtin_amdgcn_mfma_f32_16x16x32_bf16(qh[s], kh, sa[fn], 0, 0, 0);
                sa[fn] = __builtin_amdgcn_mfma_f32_16x16x32_bf16(qh[s], kl, sa[fn], 0, 0, 0);
                sa[fn] = __builtin_amdgcn_mfma_f32_16x16x32_bf16(ql[s], kh, sa[fn], 0, 0, 0);
            }
        }
        __builtin_amdgcn_s_setprio(0);

        // ---- mask tail keys (last tile only; wave-uniform branch) ----
        if (kb + 32 > nk) {
#pragma unroll
            for (int fn = 0; fn < 2; ++fn) {
                bool oob = (kb + fn * 16 + lc) >= nk;
#pragma unroll
                for (int rr = 0; rr < 4; ++rr)
                    sa[fn][rr] = oob ? -1e30f : sa[fn][rr];
            }
        }

        // ---- exp (max-free), accumulate row sums, split+pack P to LDS ----
#pragma unroll
        for (int fn = 0; fn < 2; ++fn)
#pragma unroll
            for (int rr = 0; rr < 4; ++rr) {
                float p = __expf(sa[fn][rr]);
                lsum[rr] += p;
                unsigned int u = __float_as_uint(p);
                float res = p - __uint_as_float(u & 0xffff0000u);
                unsigned int lo16 = __float_as_uint(res) >> 16;
                Pb[pbase + (lg * 4 + rr) * 36 + fn * 16 + lc] =
                    (lo16 << 16) | (u >> 16);
            }

        // ---- P: LDS -> A-frags (per-wave region; no barrier needed) ----
        const unsigned int* pr = &Pb[pbase + lc * 36 + lg * 8];
        uint4 a0 = *(const uint4*)pr;
        uint4 a1 = *(const uint4*)(pr + 4);
        FragU PH, PL;
        PH.u[0] = (a0.x & 0xffffu) | (a0.y << 16);
        PH.u[1] = (a0.z & 0xffffu) | (a0.w << 16);
        PH.u[2] = (a1.x & 0xffffu) | (a1.y << 16);
        PH.u[3] = (a1.z & 0xffffu) | (a1.w << 16);
        PL.u[0] = (a0.x >> 16) | (a0.y & 0xffff0000u);
        PL.u[1] = (a0.z >> 16) | (a0.w & 0xffff0000u);
        PL.u[2] = (a1.x >> 16) | (a1.y & 0xffff0000u);
        PL.u[3] = (a1.z >> 16) | (a1.w & 0xffff0000u);

        // ---- O += P V (16x128 per wave) ----
        __builtin_amdgcn_s_setprio(1);
#pragma unroll
        for (int fd = 0; fd < 8; ++fd) {
            int d = fd * 16 + lc;
            int ro = d * 64;
            int ph = lg ^ (d & 7);
            int pl2 = (4 + lg) ^ (d & 7);
            bf16x8 vh = *(const bf16x8*)&Vs[ro + ph * 8];
            bf16x8 vl = *(const bf16x8*)&Vs[ro + pl2 * 8];
            oacc[fd] = __builtin_amdgcn_mfma_f32_16x16x32_bf16(PH.f, vh, oacc[fd], 0, 0, 0);
            oacc[fd] = __builtin_amdgcn_mfma_f32_16x16x32_bf16(PH.f, vl, oacc[fd], 0, 0, 0);
            oacc[fd] = __builtin_amdgcn_mfma_f32_16x16x32_bf16(PL.f, vh, oacc[fd], 0, 0, 0);
        }
        __builtin_amdgcn_s_setprio(0);
        __syncthreads();   // protect Ks/Vs before next stage
    }

    // ---- reduce row sums across the 16 lanes of each quad group ----
#pragma unroll
    for (int m = 1; m < 16; m <<= 1)
#pragma unroll
        for (int rr = 0; rr < 4; ++rr)
            lsum[rr] += __shfl_xor(lsum[rr], m, 64);

    // ---- normalize, query-mask, split, store (in-place over Qhi/Qlo) ----
#pragma unroll
    for (int rr = 0; rr < 4; ++rr) {
        int q = q0 + (w << 4) + (lg << 2) + rr;
        bool valid = q < nk;
        float inv = valid ? (1.f / lsum[rr]) : 0.f;
        size_t base = (size_t)(b * Lsz + q) * Dsz + h * Dh + lc;
#pragma unroll
        for (int fd = 0; fd < 8; ++fd) {
            float val = valid ? oacc[fd][rr] * inv : 0.f;
            unsigned int u = __float_as_uint(val);
            float res = val - __uint_as_float(u & 0xffff0000u);
            Ohi[base + fd * 16] = (unsigned short)(u >> 16);
            Olo[base + fd * 16] = (unsigned short)(__float_as_uint(res) >> 16);
        }
    }
}

// ---------------------------------------------------------------------------
// ws: Qhi|Qlo|Khi|Klo|Vthi|Vtlo (6 x MD ushort) + Wfh|Wfl (fused QKV weights,
// 2 x 3WD) + Woh|Wol (2 x WD) = 6 MD + 8 WD ushort = 117.4 MB (validated).
// 4 launches total: conv_w4, gemm_qkv, flash_mfma, gemm_o.
// ---------------------------------------------------------------------------
extern "C" void kernel_launch(void* const* d_in, const int* in_sizes, int n_in,
                              void* d_out, int out_size, void* d_ws, size_t ws_size,
                              hipStream_t stream) {
    (void)in_sizes; (void)n_in; (void)out_size; (void)ws_size;
    const float* queries = (const float*)d_in[0];
    const float* keys    = (const float*)d_in[1];
    const int*   slen    = (const int*)d_in[2];
    const float* Wq      = (const float*)d_in[3];
    const float* Wk      = (const float*)d_in[4];
    const float* Wv      = (const float*)d_in[5];
    const float* Wo      = (const float*)d_in[6];
    float* out = (float*)d_out;

    const size_t MD = (size_t)Bsz * Lsz * Dsz;   // 8388608
    const size_t WD = (size_t)Dsz * Dsz;         // 1048576
    ushort* Qhi  = (ushort*)d_ws;
    ushort* Qlo  = Qhi + MD;
    ushort* Khi  = Qlo + MD;
    ushort* Klo  = Khi + MD;
    ushort* Vthi = Klo + MD;
    ushort* Vtlo = Vthi + MD;
    ushort* Wfh  = Vtlo + MD;      // fused: rows [0,1024)=Wq*s, [1024,2048)=Wk, [2048,3072)=Wv
    ushort* Wfl  = Wfh + 3 * WD;
    ushort* Woh  = Wfl + 3 * WD;
    ushort* Wol  = Woh + WD;

    const float scaleQ = 0.08838834764831845f;   // 1/sqrt(Dh), folded into Wq
    WConv4 wa;
    wa.w[0] = (const float4*)Wq; wa.h[0] = (ushort4*)Wfh;            wa.l[0] = (ushort4*)Wfl;            wa.s[0] = scaleQ;
    wa.w[1] = (const float4*)Wk; wa.h[1] = (ushort4*)(Wfh + WD);     wa.l[1] = (ushort4*)(Wfl + WD);     wa.s[1] = 1.f;
    wa.w[2] = (const float4*)Wv; wa.h[2] = (ushort4*)(Wfh + 2 * WD); wa.l[2] = (ushort4*)(Wfl + 2 * WD); wa.s[2] = 1.f;
    wa.w[3] = (const float4*)Wo; wa.h[3] = (ushort4*)Woh;            wa.l[3] = (ushort4*)Wol;            wa.s[3] = 1.f;
    conv_w4<<<4096, 256, 0, stream>>>(wa);

    // fused Q+K+V projections: N = 3072, grid (24, 64), 512 threads
    gemm_qkv<<<dim3(24, 64), 512, 0, stream>>>(
        queries, keys, Wfh, Wfl, Qhi, Qlo, Khi, Klo, Vthi, Vtlo, slen);

    // flash attention: 64-row q-tiles, 256 threads (4 waves)
    dim3 ga(Lsz / 64, Hn, Bsz);        // (32, 8, 4)
    flash_mfma<<<ga, 256, 0, stream>>>(Qhi, Qlo, Khi, Klo, Vthi, Vtlo, slen,
                                       Qhi, Qlo /* O in-place */);

    // output projection (reads pre-split O; masked tiles -> zeros)
    gemm_o<<<dim3(8, 64), 512, 0, stream>>>(Qhi, Qlo, Woh, Wol, out, slen);
}

// Round 13
// 396.115 us; speedup vs baseline: 3.4019x; 3.4019x over previous
//
#include <hip/hip_runtime.h>
#include <math.h>

// Problem constants (B, L, D, H from the reference)
constexpr int Bsz = 4;
constexpr int Lsz = 2048;
constexpr int Dsz = 1024;
constexpr int Hn  = 8;
constexpr int Dh  = 128;   // Dsz / Hn
constexpr int GM  = Bsz * Lsz;   // 8192
constexpr int GK  = Dsz;         // 1024 (K dim of every projection GEMM)
constexpr int NT  = GK / 32;     // 32 K-tiles of BK=32

typedef __attribute__((ext_vector_type(8))) short bf16x8;
typedef __attribute__((ext_vector_type(4))) float f32x4;

union FragU { unsigned int u[4]; bf16x8 f; };

// async global->LDS, 16B per lane (wave-uniform base + lane*16 dest)
__device__ __forceinline__ void gload16(const void* g, void* l) {
    __builtin_amdgcn_global_load_lds(
        (const __attribute__((address_space(1))) unsigned int*)g,
        (__attribute__((address_space(3))) unsigned int*)l, 16, 0, 0);
}

// split two fp32 into packed bf16 hi-pair / lo-pair (hi=truncate, lo=residual)
__device__ __forceinline__ void split2(float f0, float f1,
                                       unsigned int& hp, unsigned int& lp) {
    unsigned int u0 = __float_as_uint(f0), u1 = __float_as_uint(f1);
    hp = (u0 >> 16) | (u1 & 0xffff0000u);
    float l0 = f0 - __uint_as_float(u0 & 0xffff0000u);
    float l1 = f1 - __uint_as_float(u1 & 0xffff0000u);
    lp = (__float_as_uint(l0) >> 16) | (__float_as_uint(l1) & 0xffff0000u);
}

__device__ __forceinline__ void split4(float4 f, ushort4& h, ushort4& l2) {
    unsigned int ux = __float_as_uint(f.x), uy = __float_as_uint(f.y),
                 uz = __float_as_uint(f.z), uw = __float_as_uint(f.w);
    h.x = (unsigned short)(ux >> 16); h.y = (unsigned short)(uy >> 16);
    h.z = (unsigned short)(uz >> 16); h.w = (unsigned short)(uw >> 16);
    float lx = f.x - __uint_as_float(ux & 0xffff0000u);
    float ly = f.y - __uint_as_float(uy & 0xffff0000u);
    float lz = f.z - __uint_as_float(uz & 0xffff0000u);
    float lw = f.w - __uint_as_float(uw & 0xffff0000u);
    l2.x = (unsigned short)(__float_as_uint(lx) >> 16);
    l2.y = (unsigned short)(__float_as_uint(ly) >> 16);
    l2.z = (unsigned short)(__float_as_uint(lz) >> 16);
    l2.w = (unsigned short)(__float_as_uint(lw) >> 16);
}

struct WConv4 {
    const float4* w[4];
    ushort4* h[4];
    ushort4* l[4];
    float s[4];
};

// 4 weights in one launch: 1024 blocks per weight (WD/4/256 = 1024)
__global__ __launch_bounds__(256) void conv_w4(WConv4 a) {
    int wi = blockIdx.x >> 10;
    int i = (blockIdx.x & 1023) * 256 + threadIdx.x;
    float4 f = a.w[wi][i];
    float s = a.s[wi];
    f.x *= s; f.y *= s; f.z *= s; f.w *= s;
    ushort4 h, l;
    split4(f, h, l);
    a.h[wi][i] = h; a.l[wi][i] = l;
}

// ---------------------------------------------------------------------------
// Shared compute core for the GEMMs:
// per wave (8 waves = 4M x 2N): 2 fm x 4 fn frags of 16x16x32 MFMA,
// 3-product split-bf16 accumulation (hi*hi + hi*lo + lo*hi).
// la = lane index into the A region (XOR-swizzled for gemm_qkv, plain l for
// gemm_o). B reads use plain l. 0 read bank conflicts either way (r3-meas).
// ---------------------------------------------------------------------------
__device__ __forceinline__ void compute_tile(const ushort* Ah, const ushort* Al,
                                             const ushort* Bh, const ushort* Bl,
                                             int wm, int wn, int l, int la,
                                             f32x4 acc[2][4]) {
    bf16x8 bh[4], bl4[4], ah[2], al[2];
#pragma unroll
    for (int fn = 0; fn < 4; ++fn) {
        int fng = wn * 4 + fn;
        bh[fn]  = *(const bf16x8*)&Bh[(fng * 64 + l) * 8];
        bl4[fn] = *(const bf16x8*)&Bl[(fng * 64 + l) * 8];
    }
#pragma unroll
    for (int fm = 0; fm < 2; ++fm) {
        int fmg = wm * 2 + fm;
        ah[fm] = *(const bf16x8*)&Ah[(fmg * 64 + la) * 8];
        al[fm] = *(const bf16x8*)&Al[(fmg * 64 + la) * 8];
    }
    __builtin_amdgcn_s_setprio(1);
#pragma unroll
    for (int fm = 0; fm < 2; ++fm)
#pragma unroll
        for (int fn = 0; fn < 4; ++fn) {
            acc[fm][fn] = __builtin_amdgcn_mfma_f32_16x16x32_bf16(
                ah[fm], bh[fn], acc[fm][fn], 0, 0, 0);
            acc[fm][fn] = __builtin_amdgcn_mfma_f32_16x16x32_bf16(
                ah[fm], bl4[fn], acc[fm][fn], 0, 0, 0);
            acc[fm][fn] = __builtin_amdgcn_mfma_f32_16x16x32_bf16(
                al[fm], bh[fn], acc[fm][fn], 0, 0, 0);
        }
    __builtin_amdgcn_s_setprio(0);
}

// split 8 consecutive fp32 (two float4) -> hi/lo bf16x8, store 16B each
__device__ __forceinline__ void split_write(ushort* Ah, ushort* Al, int aw,
                                            float4 v0, float4 v1) {
    uint4 h4, l4;
    split2(v0.x, v0.y, h4.x, l4.x);
    split2(v0.z, v0.w, h4.y, l4.y);
    split2(v1.x, v1.y, h4.z, l4.z);
    split2(v1.z, v1.w, h4.w, l4.w);
    *(uint4*)&Ah[aw] = h4;
    *(uint4*)&Al[aw] = l4;
}

// ---------------------------------------------------------------------------
// Fused QKV projection GEMM. N = 3072 over fused weights [Wq*s; Wk; Wv].
// v13 = v12's SINGLE-BUFFER structure with the launch bound FIXED.
// r12 post-mortem: __launch_bounds__(512,8) clamped VGPR to 32 -> acc spilled
// to scratch (FETCH 152MB -> 1.7GB, MfmaUtil 3%, 1096us). The bound was the
// bug, not the structure. With (512,2) the allocator naturally picks ~64 VGPR
// (r11 measured) which ALREADY permits 8 waves/SIMD; occupancy then =
// min(LDS 160/32=5, threads 2048/512=4, VGPR@64=4) = 4 blocks/CU vs r11's 2.
// Rationale (flash r7/r8/r10 on this workload): single-buffer + more
// co-resident blocks beats dbuf + fewer (m114 inter-block TLP).
// Loop: stage B(t) gload + split_write A(t) -> sync -> issue A(t+1) reg
// loads (land under compute) -> compute(t) -> sync.
// A-layout XOR-swizzle kept (r9: conflicts 1.0e7 -> 0). Numerics identical.
// Outputs: cols [0,1024)->Qhi/Qlo; [1024,2048)->Khi/Klo row-major;
// [2048,3072)->Vthi/Vtlo TRANSPOSED. Row-tiles fully >= slen skip entirely.
// ---------------------------------------------------------------------------
__global__ __launch_bounds__(512, 2) void gemm_qkv(
    const float* __restrict__ Aq, const float* __restrict__ Ak,
    const ushort* __restrict__ Wfh, const ushort* __restrict__ Wfl,
    ushort* __restrict__ Qhi, ushort* __restrict__ Qlo,
    ushort* __restrict__ Khi, ushort* __restrict__ Klo,
    ushort* __restrict__ Vthi, ushort* __restrict__ Vtlo,
    const int* __restrict__ slen)
{
    const int tid = threadIdx.x;
    const int bm = blockIdx.y << 7;
    const int bn = blockIdx.x << 7;        // 0..2944 (fused N = 3072)
    const int grp = bn >> 10;              // 0:Q 1:K 2:V

    const int nk = slen[bm >> 11];
    if ((bm & (Lsz - 1)) >= nk) return;    // skipped tile, never read downstream

    // [region][128*32]; 0=A_hi 1=A_lo 2=B_hi 3=B_lo -> 32 KB single buffer
    __shared__ __align__(16) ushort lds[4][128 * 32];

    const float* A = (grp == 0) ? Aq : Ak;
    const int w  = tid >> 6;
    const int l  = tid & 63;
    const int wm = w >> 1;                 // 0..3 (M)
    const int wn = w & 1;                  // 0..1 (N)
    const int la = l ^ ((l >> 4) << 1);    // swizzled A frag-read lane index

    // A staging: thread owns row arow, 8 consecutive k at k-group kg
    // (32B/thread, 4 threads per 128B row -> full coalescing).
    const int arow = tid >> 2;
    const int kg   = tid & 3;
    const float* ag = A + (size_t)(bm + arow) * GK + (kg << 3);
    const int aw = ((((arow >> 4) << 6) + (kg << 4) + ((arow & 15) ^ (kg << 1))) << 3);

    // B staging: 512 threads x one 16B chunk each of hi and lo per K-tile
    const int brow = ((tid >> 6) << 4) + (tid & 15);
    const int bkk  = ((tid >> 4) & 3) << 3;
    const ushort* bgh = Wfh + (size_t)(bn + brow) * GK + bkk;
    const ushort* bgl = Wfl + (size_t)(bn + brow) * GK + bkk;

    f32x4 acc[2][4];
#pragma unroll
    for (int i = 0; i < 2; ++i)
#pragma unroll
        for (int j = 0; j < 4; ++j) acc[i][j] = (f32x4)0.f;

    // ---- prologue: A(0) -> regs -------------------------------------------
    float4 c0 = *(const float4*)(ag);
    float4 c1 = *(const float4*)(ag + 4);

    for (int t = 0; t < NT; ++t) {
        // stage tile t: B via gload_lds, A via reg+split ds_write
        gload16(bgh + t * 32, &lds[2][tid * 8]);
        gload16(bgl + t * 32, &lds[3][tid * 8]);
        split_write(&lds[0][0], &lds[1][0], aw, c0, c1);
        __syncthreads();                   // tile t fully staged (vmcnt+lgkm)
        if (t + 1 < NT) {                  // A(t+1) -> regs; lands under compute
            c0 = *(const float4*)(ag + (t + 1) * 32);
            c1 = *(const float4*)(ag + (t + 1) * 32 + 4);
        }
        compute_tile(&lds[0][0], &lds[1][0], &lds[2][0], &lds[3][0],
                     wm, wn, l, la, acc);
        __syncthreads();                   // all reads done before next stage
    }

    // epilogue: C/D layout row=(l>>4)*4+reg, col=l&15 (m89-verified)
    const int rq = (l >> 4) << 2;
    const int cq = l & 15;
    ushort* OH = (grp == 0) ? Qhi : Khi;   // grp 2 handled below
    ushort* OL = (grp == 0) ? Qlo : Klo;
#pragma unroll
    for (int fm = 0; fm < 2; ++fm) {
        int r0 = bm + wm * 32 + fm * 16 + rq;
#pragma unroll
        for (int fn = 0; fn < 4; ++fn) {
            int cn = (bn & 1023) + wn * 64 + fn * 16 + cq;
            if (grp < 2) {   // Q or K: row-major hi/lo
#pragma unroll
                for (int r = 0; r < 4; ++r) {
                    float f = acc[fm][fn][r];
                    unsigned int u = __float_as_uint(f);
                    float res = f - __uint_as_float(u & 0xffff0000u);
                    OH[(size_t)(r0 + r) * Dsz + cn] = (unsigned short)(u >> 16);
                    OL[(size_t)(r0 + r) * Dsz + cn] =
                        (unsigned short)(__float_as_uint(res) >> 16);
                }
            } else {         // V: transposed hi/lo
                ushort4 h4, l4;
                unsigned short* hp = (unsigned short*)&h4;
                unsigned short* lp = (unsigned short*)&l4;
#pragma unroll
                for (int r = 0; r < 4; ++r) {
                    float f = acc[fm][fn][r];
                    unsigned int u = __float_as_uint(f);
                    float res = f - __uint_as_float(u & 0xffff0000u);
                    hp[r] = (unsigned short)(u >> 16);
                    lp[r] = (unsigned short)(__float_as_uint(res) >> 16);
                }
                *(ushort4*)&Vthi[(size_t)cn * GM + r0] = h4;
                *(ushort4*)&Vtlo[(size_t)cn * GM + r0] = l4;
            }
        }
    }
}

// ---------------------------------------------------------------------------
// O-projection GEMM: out = O @ Wo^T, fp32 result. A pre-split (flash epilogue).
// ROUND-2 v3 unchanged: 2-phase (STAGE(t+1) -> compute(t) -> sync), all four
// operand tiles via global_load_lds (linear LDS, 0 conflicts), 512 thr,
// 64 KB LDS. Skipped row-tiles write zeros.
// ---------------------------------------------------------------------------
__global__ __launch_bounds__(512, 2) void gemm_o(
    const ushort* __restrict__ Ahi, const ushort* __restrict__ Alo,
    const ushort* __restrict__ Bhi, const ushort* __restrict__ Blo,
    float* __restrict__ C, const int* __restrict__ slen)
{
    const int tid = threadIdx.x;
    const int bm = blockIdx.y << 7;
    const int bn = blockIdx.x << 7;

    const int nk = slen[bm >> 11];
    if ((bm & (Lsz - 1)) >= nk) {
        int row = tid >> 2;
        int cb  = (tid & 3) << 5;          // 4 col-chunks of 32 floats
        float4 z = make_float4(0.f, 0.f, 0.f, 0.f);
        float4* cp = (float4*)(C + (size_t)(bm + row) * Dsz + bn + cb);
#pragma unroll
        for (int i = 0; i < 8; ++i) cp[i] = z;
        return;
    }

    __shared__ __align__(16) ushort lds[2][4][128 * 32];

    const int w  = tid >> 6;
    const int l  = tid & 63;
    const int wm = w >> 1;
    const int wn = w & 1;

    const int srow = ((tid >> 6) << 4) + (tid & 15);
    const int skk  = ((tid >> 4) & 3) << 3;
    const ushort* agh = Ahi + (size_t)(bm + srow) * GK + skk;
    const ushort* agl = Alo + (size_t)(bm + srow) * GK + skk;
    const ushort* bgh = Bhi + (size_t)(bn + srow) * GK + skk;
    const ushort* bgl = Blo + (size_t)(bn + srow) * GK + skk;

    f32x4 acc[2][4];
#pragma unroll
    for (int i = 0; i < 2; ++i)
#pragma unroll
        for (int j = 0; j < 4; ++j) acc[i][j] = (f32x4)0.f;

    // prologue: stage tile 0 -> buf0, drain, barrier
    gload16(agh, &lds[0][0][tid * 8]);
    gload16(agl, &lds[0][1][tid * 8]);
    gload16(bgh, &lds[0][2][tid * 8]);
    gload16(bgl, &lds[0][3][tid * 8]);
    __syncthreads();

    for (int t = 0; t < NT - 1; ++t) {
        const int p = t & 1;
        const int q = p ^ 1;
        gload16(agh + (t + 1) * 32, &lds[q][0][tid * 8]);
        gload16(agl + (t + 1) * 32, &lds[q][1][tid * 8]);
        gload16(bgh + (t + 1) * 32, &lds[q][2][tid * 8]);
        gload16(bgl + (t + 1) * 32, &lds[q][3][tid * 8]);
        compute_tile(&lds[p][0][0], &lds[p][1][0], &lds[p][2][0], &lds[p][3][0],
                     wm, wn, l, l, acc);
        __syncthreads();
    }
    {
        const int p = (NT - 1) & 1;
        compute_tile(&lds[p][0][0], &lds[p][1][0], &lds[p][2][0], &lds[p][3][0],
                     wm, wn, l, l, acc);
    }

    const int rq = (l >> 4) << 2;
    const int cq = l & 15;
#pragma unroll
    for (int fm = 0; fm < 2; ++fm) {
        int r0 = bm + wm * 32 + fm * 16 + rq;
#pragma unroll
        for (int fn = 0; fn < 4; ++fn) {
            int c0 = bn + wn * 64 + fn * 16 + cq;
#pragma unroll
            for (int r = 0; r < 4; ++r)
                C[(size_t)(r0 + r) * Dsz + c0] = acc[fm][fn][r];
        }
    }
}

// ---------------------------------------------------------------------------
// MFMA flash attention, split-bf16, max-free online softmax.
// r11-MEASURED BEST (unchanged): BQ=64 (256 thr = 4 waves, 16 q-rows per
// wave), BK=32, SINGLE-buffered 41 KB LDS, gload_lds -> __syncthreads,
// T5 s_setprio(1/0) around the QK and PV MFMA clusters.
// LDS lesson (r5 T14, r10 dbuf both regressed): flash's latency hiding comes
// from INTER-BLOCK TLP (3 blocks/CU at 41 KB); any intra-block overlap that
// grows LDS to 73 KB cuts capacity to 2 and loses more than it gains.
// BQ sweep measured: 128 -> 160us, 64 -> ~125us (best), 32 -> 162us.
// SKIP LOGIC: gemm_o zero-skips at 128-row granularity, so a 64-tile whose
// parent 128-tile is live but whose own q0 >= nk must WRITE ZEROS.
// O written pre-split in-place over Qhi/Qlo.
// ---------------------------------------------------------------------------
__global__ __launch_bounds__(256) void flash_mfma(
    const ushort* __restrict__ Qhi, const ushort* __restrict__ Qlo,
    const ushort* __restrict__ Khi, const ushort* __restrict__ Klo,
    const ushort* __restrict__ Vthi, const ushort* __restrict__ Vtlo,
    const int* __restrict__ slen,
    ushort* __restrict__ Ohi, ushort* __restrict__ Olo)
{
    __shared__ __align__(16) ushort Ks[32 * 256];           // 16 KB
    __shared__ __align__(16) ushort Vs[128 * 64];           // 16 KB
    __shared__ __align__(16) unsigned int Pb[4 * 16 * 36];  // 9 KB

    const int tid = threadIdx.x;
    const int w = tid >> 6, l = tid & 63;
    const int lg = l >> 4, lc = l & 15;
    const int q0 = blockIdx.x << 6;        // 64-row q-tile
    const int h = blockIdx.y, b = blockIdx.z;
    const int nk = slen[b];

    if ((q0 & ~127) >= nk) return;         // parent 128-tile skipped by gemm_o

    if (q0 >= nk) {
        // parent tile live but this half fully masked: write zeros so gemm_o
        // never reads stale Q rows.
#pragma unroll
        for (int rr = 0; rr < 4; ++rr) {
            int q = q0 + (w << 4) + (lg << 2) + rr;
            size_t base = (size_t)(b * Lsz + q) * Dsz + h * Dh + lc;
#pragma unroll
            for (int fd = 0; fd < 8; ++fd) {
                Ohi[base + fd * 16] = 0;
                Olo[base + fd * 16] = 0;
            }
        }
        return;
    }

    // ---- Q strip -> A-frags (pre-split bf16), once per block ----
    bf16x8 qh[4], ql[4];
    {
        size_t base = (size_t)(b * Lsz + q0 + (w << 4) + lc) * Dsz + h * Dh + lg * 8;
#pragma unroll
        for (int s = 0; s < 4; ++s) {
            qh[s] = *(const bf16x8*)&Qhi[base + s * 32];
            ql[s] = *(const bf16x8*)&Qlo[base + s * 32];
        }
    }

    // ---- staging decode (256 threads, 1024 chunks each of K and Vt) ----
    const ushort* ksrc[4]; int klds[4];
    const ushort* vsrc[4]; int vlds[4];
#pragma unroll
    for (int i = 0; i < 4; ++i) {
        int s = i * 256 + tid;              // K chunk: row j (32ch: 16 hi + 16 lo)
        int j = s >> 5, p = s & 31;
        int lg4 = (p & 15) ^ (j & 15);
        const ushort* base = (p & 16) ? Klo : Khi;
        ksrc[i] = base + (size_t)(b * Lsz + j) * Dsz + h * Dh + lg4 * 8;
        klds[i] = s * 8;
    }
#pragma unroll
    for (int i = 0; i < 4; ++i) {
        int s = i * 256 + tid;              // Vt chunk: row d (8ch: 4 hi + 4 lo)
        int d = s >> 3, p = s & 7;
        int lgc = p ^ (d & 7);
        const ushort* base = (lgc & 4) ? Vtlo : Vthi;
        vsrc[i] = base + (size_t)(h * Dh + d) * (Bsz * Lsz) + b * Lsz + (lgc & 3) * 8;
        vlds[i] = s * 8;
    }

    f32x4 oacc[8];
#pragma unroll
    for (int fd = 0; fd < 8; ++fd) oacc[fd] = (f32x4)0.f;
    float lsum[4] = {0.f, 0.f, 0.f, 0.f};
    const int pbase = w * (16 * 36);

    for (int kb = 0; kb < nk; kb += 32) {
        // ---- stage K + V^T tiles ----
#pragma unroll
        for (int i = 0; i < 4; ++i) gload16(ksrc[i] + (size_t)kb * Dsz, &Ks[klds[i]]);
#pragma unroll
        for (int i = 0; i < 4; ++i) gload16(vsrc[i] + kb, &Vs[vlds[i]]);
        __syncthreads();

        // ---- S = Q K^T (16x32 per wave) ----
        f32x4 sa[2] = {(f32x4)0.f, (f32x4)0.f};
        __builtin_amdgcn_s_setprio(1);
#pragma unroll
        for (int fn = 0; fn < 2; ++fn) {
            int j = fn * 16 + lc;
            int ro = j * 256;
#pragma unroll
            for (int s = 0; s < 4; ++s) {
                int phys = (s * 4 + lg) ^ (j & 15);
                bf16x8 kh = *(const bf16x8*)&Ks[ro + phys * 8];
                bf16x8 kl = *(const bf16x8*)&Ks[ro + 128 + phys * 8];
                sa[fn] = __builtin_amdgcn_mfma_f32_16x16x32_bf16(qh[s], kh, sa[fn], 0, 0, 0);
                sa[fn] = __builtin_amdgcn_mfma_f32_16x16x32_bf16(qh[s], kl, sa[fn], 0, 0, 0);
                sa[fn] = __builtin_amdgcn_mfma_f32_16x16x32_bf16(ql[s], kh, sa[fn], 0, 0, 0);
            }
        }
        __builtin_amdgcn_s_setprio(0);

        // ---- mask tail keys (last tile only; wave-uniform branch) ----
        if (kb + 32 > nk) {
#pragma unroll
            for (int fn = 0; fn < 2; ++fn) {
                bool oob = (kb + fn * 16 + lc) >= nk;
#pragma unroll
                for (int rr = 0; rr < 4; ++rr)
                    sa[fn][rr] = oob ? -1e30f : sa[fn][rr];
            }
        }

        // ---- exp (max-free), accumulate row sums, split+pack P to LDS ----
#pragma unroll
        for (int fn = 0; fn < 2; ++fn)
#pragma unroll
            for (int rr = 0; rr < 4; ++rr) {
                float p = __expf(sa[fn][rr]);
                lsum[rr] += p;
                unsigned int u = __float_as_uint(p);
                float res = p - __uint_as_float(u & 0xffff0000u);
                unsigned int lo16 = __float_as_uint(res) >> 16;
                Pb[pbase + (lg * 4 + rr) * 36 + fn * 16 + lc] =
                    (lo16 << 16) | (u >> 16);
            }

        // ---- P: LDS -> A-frags (per-wave region; no barrier needed) ----
        const unsigned int* pr = &Pb[pbase + lc * 36 + lg * 8];
        uint4 a0 = *(const uint4*)pr;
        uint4 a1 = *(const uint4*)(pr + 4);
        FragU PH, PL;
        PH.u[0] = (a0.x & 0xffffu) | (a0.y << 16);
        PH.u[1] = (a0.z & 0xffffu) | (a0.w << 16);
        PH.u[2] = (a1.x & 0xffffu) | (a1.y << 16);
        PH.u[3] = (a1.z & 0xffffu) | (a1.w << 16);
        PL.u[0] = (a0.x >> 16) | (a0.y & 0xffff0000u);
        PL.u[1] = (a0.z >> 16) | (a0.w & 0xffff0000u);
        PL.u[2] = (a1.x >> 16) | (a1.y & 0xffff0000u);
        PL.u[3] = (a1.z >> 16) | (a1.w & 0xffff0000u);

        // ---- O += P V (16x128 per wave) ----
        __builtin_amdgcn_s_setprio(1);
#pragma unroll
        for (int fd = 0; fd < 8; ++fd) {
            int d = fd * 16 + lc;
            int ro = d * 64;
            int ph = lg ^ (d & 7);
            int pl2 = (4 + lg) ^ (d & 7);
            bf16x8 vh = *(const bf16x8*)&Vs[ro + ph * 8];
            bf16x8 vl = *(const bf16x8*)&Vs[ro + pl2 * 8];
            oacc[fd] = __builtin_amdgcn_mfma_f32_16x16x32_bf16(PH.f, vh, oacc[fd], 0, 0, 0);
            oacc[fd] = __builtin_amdgcn_mfma_f32_16x16x32_bf16(PH.f, vl, oacc[fd], 0, 0, 0);
            oacc[fd] = __builtin_amdgcn_mfma_f32_16x16x32_bf16(PL.f, vh, oacc[fd], 0, 0, 0);
        }
        __builtin_amdgcn_s_setprio(0);
        __syncthreads();   // protect Ks/Vs before next stage
    }

    // ---- reduce row sums across the 16 lanes of each quad group ----
#pragma unroll
    for (int m = 1; m < 16; m <<= 1)
#pragma unroll
        for (int rr = 0; rr < 4; ++rr)
            lsum[rr] += __shfl_xor(lsum[rr], m, 64);

    // ---- normalize, query-mask, split, store (in-place over Qhi/Qlo) ----
#pragma unroll
    for (int rr = 0; rr < 4; ++rr) {
        int q = q0 + (w << 4) + (lg << 2) + rr;
        bool valid = q < nk;
        float inv = valid ? (1.f / lsum[rr]) : 0.f;
        size_t base = (size_t)(b * Lsz + q) * Dsz + h * Dh + lc;
#pragma unroll
        for (int fd = 0; fd < 8; ++fd) {
            float val = valid ? oacc[fd][rr] * inv : 0.f;
            unsigned int u = __float_as_uint(val);
            float res = val - __uint_as_float(u & 0xffff0000u);
            Ohi[base + fd * 16] = (unsigned short)(u >> 16);
            Olo[base + fd * 16] = (unsigned short)(__float_as_uint(res) >> 16);
        }
    }
}

// ---------------------------------------------------------------------------
// ws: Qhi|Qlo|Khi|Klo|Vthi|Vtlo (6 x MD ushort) + Wfh|Wfl (fused QKV weights,
// 2 x 3WD) + Woh|Wol (2 x WD) = 6 MD + 8 WD ushort = 117.4 MB (validated).
// 4 launches total: conv_w4, gemm_qkv, flash_mfma, gemm_o.
// ---------------------------------------------------------------------------
extern "C" void kernel_launch(void* const* d_in, const int* in_sizes, int n_in,
                              void* d_out, int out_size, void* d_ws, size_t ws_size,
                              hipStream_t stream) {
    (void)in_sizes; (void)n_in; (void)out_size; (void)ws_size;
    const float* queries = (const float*)d_in[0];
    const float* keys    = (const float*)d_in[1];
    const int*   slen    = (const int*)d_in[2];
    const float* Wq      = (const float*)d_in[3];
    const float* Wk      = (const float*)d_in[4];
    const float* Wv      = (const float*)d_in[5];
    const float* Wo      = (const float*)d_in[6];
    float* out = (float*)d_out;

    const size_t MD = (size_t)Bsz * Lsz * Dsz;   // 8388608
    const size_t WD = (size_t)Dsz * Dsz;         // 1048576
    ushort* Qhi  = (ushort*)d_ws;
    ushort* Qlo  = Qhi + MD;
    ushort* Khi  = Qlo + MD;
    ushort* Klo  = Khi + MD;
    ushort* Vthi = Klo + MD;
    ushort* Vtlo = Vthi + MD;
    ushort* Wfh  = Vtlo + MD;      // fused: rows [0,1024)=Wq*s, [1024,2048)=Wk, [2048,3072)=Wv
    ushort* Wfl  = Wfh + 3 * WD;
    ushort* Woh  = Wfl + 3 * WD;
    ushort* Wol  = Woh + WD;

    const float scaleQ = 0.08838834764831845f;   // 1/sqrt(Dh), folded into Wq
    WConv4 wa;
    wa.w[0] = (const float4*)Wq; wa.h[0] = (ushort4*)Wfh;            wa.l[0] = (ushort4*)Wfl;            wa.s[0] = scaleQ;
    wa.w[1] = (const float4*)Wk; wa.h[1] = (ushort4*)(Wfh + WD);     wa.l[1] = (ushort4*)(Wfl + WD);     wa.s[1] = 1.f;
    wa.w[2] = (const float4*)Wv; wa.h[2] = (ushort4*)(Wfh + 2 * WD); wa.l[2] = (ushort4*)(Wfl + 2 * WD); wa.s[2] = 1.f;
    wa.w[3] = (const float4*)Wo; wa.h[3] = (ushort4*)Woh;            wa.l[3] = (ushort4*)Wol;            wa.s[3] = 1.f;
    conv_w4<<<4096, 256, 0, stream>>>(wa);

    // fused Q+K+V projections: N = 3072, grid (24, 64), 512 threads
    gemm_qkv<<<dim3(24, 64), 512, 0, stream>>>(
        queries, keys, Wfh, Wfl, Qhi, Qlo, Khi, Klo, Vthi, Vtlo, slen);

    // flash attention: 64-row q-tiles, 256 threads (4 waves)
    dim3 ga(Lsz / 64, Hn, Bsz);        // (32, 8, 4)
    flash_mfma<<<ga, 256, 0, stream>>>(Qhi, Qlo, Khi, Klo, Vthi, Vtlo, slen,
                                       Qhi, Qlo /* O in-place */);

    // output projection (reads pre-split O; masked tiles -> zeros)
    gemm_o<<<dim3(8, 64), 512, 0, stream>>>(Qhi, Qlo, Woh, Wol, out, slen);
}

// Round 14
// 385.220 us; speedup vs baseline: 3.4981x; 1.0283x over previous
//
#include <hip/hip_runtime.h>
#include <math.h>

// Problem constants (B, L, D, H from the reference)
constexpr int Bsz = 4;
constexpr int Lsz = 2048;
constexpr int Dsz = 1024;
constexpr int Hn  = 8;
constexpr int Dh  = 128;   // Dsz / Hn
constexpr int GM  = Bsz * Lsz;   // 8192
constexpr int GK  = Dsz;         // 1024 (K dim of every projection GEMM)
constexpr int NT  = GK / 32;     // 32 K-tiles of BK=32

typedef __attribute__((ext_vector_type(8))) short bf16x8;
typedef __attribute__((ext_vector_type(4))) float f32x4;

union FragU { unsigned int u[4]; bf16x8 f; };

// async global->LDS, 16B per lane (wave-uniform base + lane*16 dest)
__device__ __forceinline__ void gload16(const void* g, void* l) {
    __builtin_amdgcn_global_load_lds(
        (const __attribute__((address_space(1))) unsigned int*)g,
        (__attribute__((address_space(3))) unsigned int*)l, 16, 0, 0);
}

// split two fp32 into packed bf16 hi-pair / lo-pair (hi=truncate, lo=residual)
__device__ __forceinline__ void split2(float f0, float f1,
                                       unsigned int& hp, unsigned int& lp) {
    unsigned int u0 = __float_as_uint(f0), u1 = __float_as_uint(f1);
    hp = (u0 >> 16) | (u1 & 0xffff0000u);
    float l0 = f0 - __uint_as_float(u0 & 0xffff0000u);
    float l1 = f1 - __uint_as_float(u1 & 0xffff0000u);
    lp = (__float_as_uint(l0) >> 16) | (__float_as_uint(l1) & 0xffff0000u);
}

__device__ __forceinline__ void split4(float4 f, ushort4& h, ushort4& l2) {
    unsigned int ux = __float_as_uint(f.x), uy = __float_as_uint(f.y),
                 uz = __float_as_uint(f.z), uw = __float_as_uint(f.w);
    h.x = (unsigned short)(ux >> 16); h.y = (unsigned short)(uy >> 16);
    h.z = (unsigned short)(uz >> 16); h.w = (unsigned short)(uw >> 16);
    float lx = f.x - __uint_as_float(ux & 0xffff0000u);
    float ly = f.y - __uint_as_float(uy & 0xffff0000u);
    float lz = f.z - __uint_as_float(uz & 0xffff0000u);
    float lw = f.w - __uint_as_float(uw & 0xffff0000u);
    l2.x = (unsigned short)(__float_as_uint(lx) >> 16);
    l2.y = (unsigned short)(__float_as_uint(ly) >> 16);
    l2.z = (unsigned short)(__float_as_uint(lz) >> 16);
    l2.w = (unsigned short)(__float_as_uint(lw) >> 16);
}

struct WConv4 {
    const float4* w[4];
    ushort4* h[4];
    ushort4* l[4];
    float s[4];
};

// 4 weights in one launch: 1024 blocks per weight (WD/4/256 = 1024)
__global__ __launch_bounds__(256) void conv_w4(WConv4 a) {
    int wi = blockIdx.x >> 10;
    int i = (blockIdx.x & 1023) * 256 + threadIdx.x;
    float4 f = a.w[wi][i];
    float s = a.s[wi];
    f.x *= s; f.y *= s; f.z *= s; f.w *= s;
    ushort4 h, l;
    split4(f, h, l);
    a.h[wi][i] = h; a.l[wi][i] = l;
}

// ---------------------------------------------------------------------------
// Shared compute core for the 2-phase GEMMs:
// per wave (8 waves = 4M x 2N): 2 fm x 4 fn frags of 16x16x32 MFMA,
// 3-product split-bf16 accumulation (hi*hi + hi*lo + lo*hi).
// la = lane index into the A region (XOR-swizzled for gemm_qkv, plain l for
// gemm_o). B reads use plain l. 0 read bank conflicts either way (r3-meas).
// ---------------------------------------------------------------------------
__device__ __forceinline__ void compute_tile(const ushort* Ah, const ushort* Al,
                                             const ushort* Bh, const ushort* Bl,
                                             int wm, int wn, int l, int la,
                                             f32x4 acc[2][4]) {
    bf16x8 bh[4], bl4[4], ah[2], al[2];
#pragma unroll
    for (int fn = 0; fn < 4; ++fn) {
        int fng = wn * 4 + fn;
        bh[fn]  = *(const bf16x8*)&Bh[(fng * 64 + l) * 8];
        bl4[fn] = *(const bf16x8*)&Bl[(fng * 64 + l) * 8];
    }
#pragma unroll
    for (int fm = 0; fm < 2; ++fm) {
        int fmg = wm * 2 + fm;
        ah[fm] = *(const bf16x8*)&Ah[(fmg * 64 + la) * 8];
        al[fm] = *(const bf16x8*)&Al[(fmg * 64 + la) * 8];
    }
    __builtin_amdgcn_s_setprio(1);
#pragma unroll
    for (int fm = 0; fm < 2; ++fm)
#pragma unroll
        for (int fn = 0; fn < 4; ++fn) {
            acc[fm][fn] = __builtin_amdgcn_mfma_f32_16x16x32_bf16(
                ah[fm], bh[fn], acc[fm][fn], 0, 0, 0);
            acc[fm][fn] = __builtin_amdgcn_mfma_f32_16x16x32_bf16(
                ah[fm], bl4[fn], acc[fm][fn], 0, 0, 0);
            acc[fm][fn] = __builtin_amdgcn_mfma_f32_16x16x32_bf16(
                al[fm], bh[fn], acc[fm][fn], 0, 0, 0);
        }
    __builtin_amdgcn_s_setprio(0);
}

// split 8 consecutive fp32 (two float4) -> hi/lo bf16x8, store 16B each
__device__ __forceinline__ void split_write(ushort* Ah, ushort* Al, int aw,
                                            float4 v0, float4 v1) {
    uint4 h4, l4;
    split2(v0.x, v0.y, h4.x, l4.x);
    split2(v0.z, v0.w, h4.y, l4.y);
    split2(v1.x, v1.y, h4.z, l4.z);
    split2(v1.z, v1.w, h4.w, l4.w);
    *(uint4*)&Ah[aw] = h4;
    *(uint4*)&Al[aw] = l4;
}

// ---------------------------------------------------------------------------
// Fused QKV projection GEMM. N = 3072 over fused weights [Wq*s; Wk; Wv].
// r11-MEASURED BEST RESTORED VERBATIM (130.5us, best of 7 structural
// variants tried r2-r13): round-2 2-phase double-buffered structure +
// A-layout XOR-swizzle (bank conflicts 1.0e7 -> 0, r9: -5us).
// Refuted alternatives: counted-vmcnt (r3 -4%), A-direct-global (r4 -83%),
// launch_bounds(512,8) (r12: VGPR clamp 32 -> spill, 8x), single-buffer
// (r13 -9%: occupancy did NOT rise, lost intra-block overlap for nothing).
// A element (row,kg) at slot (row>>4)*64 + kg*16 + ((row&15)^(kg<<1));
// frag read uses la = l ^ ((l>>4)<<1).
// Outputs: cols [0,1024)->Qhi/Qlo; [1024,2048)->Khi/Klo row-major;
// [2048,3072)->Vthi/Vtlo TRANSPOSED. Row-tiles fully >= slen skip entirely.
// ---------------------------------------------------------------------------
__global__ __launch_bounds__(512, 2) void gemm_qkv(
    const float* __restrict__ Aq, const float* __restrict__ Ak,
    const ushort* __restrict__ Wfh, const ushort* __restrict__ Wfl,
    ushort* __restrict__ Qhi, ushort* __restrict__ Qlo,
    ushort* __restrict__ Khi, ushort* __restrict__ Klo,
    ushort* __restrict__ Vthi, ushort* __restrict__ Vtlo,
    const int* __restrict__ slen)
{
    const int tid = threadIdx.x;
    const int bm = blockIdx.y << 7;
    const int bn = blockIdx.x << 7;        // 0..2944 (fused N = 3072)
    const int grp = bn >> 10;              // 0:Q 1:K 2:V

    const int nk = slen[bm >> 11];
    if ((bm & (Lsz - 1)) >= nk) return;    // skipped tile, never read downstream

    // [buf][region][128*32]; regions: 0=A_hi 1=A_lo 2=B_hi 3=B_lo -> 64 KB
    __shared__ __align__(16) ushort lds[2][4][128 * 32];

    const float* A = (grp == 0) ? Aq : Ak;
    const int w  = tid >> 6;
    const int l  = tid & 63;
    const int wm = w >> 1;                 // 0..3 (M)
    const int wn = w & 1;                  // 0..1 (N)
    const int la = l ^ ((l >> 4) << 1);    // swizzled A frag-read lane index

    // A staging: thread owns row arow, 8 consecutive k at k-group kg
    // (32B/thread, 4 threads per 128B row -> full coalescing).
    const int arow = tid >> 2;
    const int kg   = tid & 3;
    const float* ag = A + (size_t)(bm + arow) * GK + (kg << 3);
    const int aw = ((((arow >> 4) << 6) + (kg << 4) + ((arow & 15) ^ (kg << 1))) << 3);

    // B staging: 512 threads x one 16B chunk each of hi and lo per K-tile
    const int brow = ((tid >> 6) << 4) + (tid & 15);
    const int bkk  = ((tid >> 4) & 3) << 3;
    const ushort* bgh = Wfh + (size_t)(bn + brow) * GK + bkk;
    const ushort* bgl = Wfl + (size_t)(bn + brow) * GK + bkk;

    f32x4 acc[2][4];
#pragma unroll
    for (int i = 0; i < 2; ++i)
#pragma unroll
        for (int j = 0; j < 4; ++j) acc[i][j] = (f32x4)0.f;

    // ---- prologue: stage tile0 (A via reg+split, B via gload), prefetch A(1)
    {
        float4 tC0 = *(const float4*)(ag);
        float4 tC1 = *(const float4*)(ag + 4);
        gload16(bgh, &lds[0][2][tid * 8]);
        gload16(bgl, &lds[0][3][tid * 8]);
        split_write(&lds[0][0][0], &lds[0][1][0], aw, tC0, tC1);
    }
    float4 rN0 = *(const float4*)(ag + 32);      // A(1)
    float4 rN1 = *(const float4*)(ag + 36);
    float4 rA0, rA1;                             // A(t+2) in even windows
    __syncthreads();

    // ---- main loop: windows 0..29 (2-unrolled; rN/rA alternate) -----------
    for (int t = 0; t < NT - 2; t += 2) {
        // even window t: stage tile t+1 -> buf1, compute buf0 (tile t)
        rA0 = *(const float4*)(ag + (t + 2) * 32);
        rA1 = *(const float4*)(ag + (t + 2) * 32 + 4);
        gload16(bgh + (t + 1) * 32, &lds[1][2][tid * 8]);
        gload16(bgl + (t + 1) * 32, &lds[1][3][tid * 8]);
        split_write(&lds[1][0][0], &lds[1][1][0], aw, rN0, rN1);  // A(t+1)
        compute_tile(&lds[0][0][0], &lds[0][1][0], &lds[0][2][0], &lds[0][3][0],
                     wm, wn, l, la, acc);
        __syncthreads();

        // odd window t+1: stage tile t+2 -> buf0, compute buf1 (tile t+1)
        rN0 = *(const float4*)(ag + (t + 3) * 32);               // A(t+3), t+3<=31
        rN1 = *(const float4*)(ag + (t + 3) * 32 + 4);
        gload16(bgh + (t + 2) * 32, &lds[0][2][tid * 8]);
        gload16(bgl + (t + 2) * 32, &lds[0][3][tid * 8]);
        split_write(&lds[0][0][0], &lds[0][1][0], aw, rA0, rA1); // A(t+2)
        compute_tile(&lds[1][0][0], &lds[1][1][0], &lds[1][2][0], &lds[1][3][0],
                     wm, wn, l, la, acc);
        __syncthreads();
    }

    // ---- window 30: stage tile 31 -> buf1, compute buf0 (tile 30) ---------
    gload16(bgh + (NT - 1) * 32, &lds[1][2][tid * 8]);
    gload16(bgl + (NT - 1) * 32, &lds[1][3][tid * 8]);
    split_write(&lds[1][0][0], &lds[1][1][0], aw, rN0, rN1);      // A(31)
    compute_tile(&lds[0][0][0], &lds[0][1][0], &lds[0][2][0], &lds[0][3][0],
                 wm, wn, l, la, acc);
    __syncthreads();

    // ---- window 31: compute buf1 (tile 31) --------------------------------
    compute_tile(&lds[1][0][0], &lds[1][1][0], &lds[1][2][0], &lds[1][3][0],
                 wm, wn, l, la, acc);

    // epilogue: C/D layout row=(l>>4)*4+reg, col=l&15 (m89-verified)
    const int rq = (l >> 4) << 2;
    const int cq = l & 15;
    ushort* OH = (grp == 0) ? Qhi : Khi;   // grp 2 handled below
    ushort* OL = (grp == 0) ? Qlo : Klo;
#pragma unroll
    for (int fm = 0; fm < 2; ++fm) {
        int r0 = bm + wm * 32 + fm * 16 + rq;
#pragma unroll
        for (int fn = 0; fn < 4; ++fn) {
            int cn = (bn & 1023) + wn * 64 + fn * 16 + cq;
            if (grp < 2) {   // Q or K: row-major hi/lo
#pragma unroll
                for (int r = 0; r < 4; ++r) {
                    float f = acc[fm][fn][r];
                    unsigned int u = __float_as_uint(f);
                    float res = f - __uint_as_float(u & 0xffff0000u);
                    OH[(size_t)(r0 + r) * Dsz + cn] = (unsigned short)(u >> 16);
                    OL[(size_t)(r0 + r) * Dsz + cn] =
                        (unsigned short)(__float_as_uint(res) >> 16);
                }
            } else {         // V: transposed hi/lo
                ushort4 h4, l4;
                unsigned short* hp = (unsigned short*)&h4;
                unsigned short* lp = (unsigned short*)&l4;
#pragma unroll
                for (int r = 0; r < 4; ++r) {
                    float f = acc[fm][fn][r];
                    unsigned int u = __float_as_uint(f);
                    float res = f - __uint_as_float(u & 0xffff0000u);
                    hp[r] = (unsigned short)(u >> 16);
                    lp[r] = (unsigned short)(__float_as_uint(res) >> 16);
                }
                *(ushort4*)&Vthi[(size_t)cn * GM + r0] = h4;
                *(ushort4*)&Vtlo[(size_t)cn * GM + r0] = l4;
            }
        }
    }
}

// ---------------------------------------------------------------------------
// O-projection GEMM: out = O @ Wo^T, fp32 result. A pre-split (flash epilogue).
// ROUND-2 v3 unchanged: 2-phase (STAGE(t+1) -> compute(t) -> sync), all four
// operand tiles via global_load_lds (linear LDS, 0 conflicts), 512 thr,
// 64 KB LDS. Skipped row-tiles write zeros.
// ---------------------------------------------------------------------------
__global__ __launch_bounds__(512, 2) void gemm_o(
    const ushort* __restrict__ Ahi, const ushort* __restrict__ Alo,
    const ushort* __restrict__ Bhi, const ushort* __restrict__ Blo,
    float* __restrict__ C, const int* __restrict__ slen)
{
    const int tid = threadIdx.x;
    const int bm = blockIdx.y << 7;
    const int bn = blockIdx.x << 7;

    const int nk = slen[bm >> 11];
    if ((bm & (Lsz - 1)) >= nk) {
        int row = tid >> 2;
        int cb  = (tid & 3) << 5;          // 4 col-chunks of 32 floats
        float4 z = make_float4(0.f, 0.f, 0.f, 0.f);
        float4* cp = (float4*)(C + (size_t)(bm + row) * Dsz + bn + cb);
#pragma unroll
        for (int i = 0; i < 8; ++i) cp[i] = z;
        return;
    }

    __shared__ __align__(16) ushort lds[2][4][128 * 32];

    const int w  = tid >> 6;
    const int l  = tid & 63;
    const int wm = w >> 1;
    const int wn = w & 1;

    const int srow = ((tid >> 6) << 4) + (tid & 15);
    const int skk  = ((tid >> 4) & 3) << 3;
    const ushort* agh = Ahi + (size_t)(bm + srow) * GK + skk;
    const ushort* agl = Alo + (size_t)(bm + srow) * GK + skk;
    const ushort* bgh = Bhi + (size_t)(bn + srow) * GK + skk;
    const ushort* bgl = Blo + (size_t)(bn + srow) * GK + skk;

    f32x4 acc[2][4];
#pragma unroll
    for (int i = 0; i < 2; ++i)
#pragma unroll
        for (int j = 0; j < 4; ++j) acc[i][j] = (f32x4)0.f;

    // prologue: stage tile 0 -> buf0, drain, barrier
    gload16(agh, &lds[0][0][tid * 8]);
    gload16(agl, &lds[0][1][tid * 8]);
    gload16(bgh, &lds[0][2][tid * 8]);
    gload16(bgl, &lds[0][3][tid * 8]);
    __syncthreads();

    for (int t = 0; t < NT - 1; ++t) {
        const int p = t & 1;
        const int q = p ^ 1;
        gload16(agh + (t + 1) * 32, &lds[q][0][tid * 8]);
        gload16(agl + (t + 1) * 32, &lds[q][1][tid * 8]);
        gload16(bgh + (t + 1) * 32, &lds[q][2][tid * 8]);
        gload16(bgl + (t + 1) * 32, &lds[q][3][tid * 8]);
        compute_tile(&lds[p][0][0], &lds[p][1][0], &lds[p][2][0], &lds[p][3][0],
                     wm, wn, l, l, acc);
        __syncthreads();
    }
    {
        const int p = (NT - 1) & 1;
        compute_tile(&lds[p][0][0], &lds[p][1][0], &lds[p][2][0], &lds[p][3][0],
                     wm, wn, l, l, acc);
    }

    const int rq = (l >> 4) << 2;
    const int cq = l & 15;
#pragma unroll
    for (int fm = 0; fm < 2; ++fm) {
        int r0 = bm + wm * 32 + fm * 16 + rq;
#pragma unroll
        for (int fn = 0; fn < 4; ++fn) {
            int c0 = bn + wn * 64 + fn * 16 + cq;
#pragma unroll
            for (int r = 0; r < 4; ++r)
                C[(size_t)(r0 + r) * Dsz + c0] = acc[fm][fn][r];
        }
    }
}

// ---------------------------------------------------------------------------
// MFMA flash attention, split-bf16, max-free online softmax.
// r11-MEASURED BEST (unchanged): BQ=64 (256 thr = 4 waves, 16 q-rows per
// wave), BK=32, SINGLE-buffered 41 KB LDS, gload_lds -> __syncthreads,
// T5 s_setprio(1/0) around the QK and PV MFMA clusters.
// LDS lesson (r5 T14, r10 dbuf both regressed): flash's latency hiding comes
// from INTER-BLOCK TLP (3 blocks/CU at 41 KB); any intra-block overlap that
// grows LDS to 73 KB cuts capacity to 2 and loses more than it gains.
// BQ sweep measured: 128 -> 160us, 64 -> ~125us (best), 32 -> 162us.
// SKIP LOGIC: gemm_o zero-skips at 128-row granularity, so a 64-tile whose
// parent 128-tile is live but whose own q0 >= nk must WRITE ZEROS.
// O written pre-split in-place over Qhi/Qlo.
// ---------------------------------------------------------------------------
__global__ __launch_bounds__(256) void flash_mfma(
    const ushort* __restrict__ Qhi, const ushort* __restrict__ Qlo,
    const ushort* __restrict__ Khi, const ushort* __restrict__ Klo,
    const ushort* __restrict__ Vthi, const ushort* __restrict__ Vtlo,
    const int* __restrict__ slen,
    ushort* __restrict__ Ohi, ushort* __restrict__ Olo)
{
    __shared__ __align__(16) ushort Ks[32 * 256];           // 16 KB
    __shared__ __align__(16) ushort Vs[128 * 64];           // 16 KB
    __shared__ __align__(16) unsigned int Pb[4 * 16 * 36];  // 9 KB

    const int tid = threadIdx.x;
    const int w = tid >> 6, l = tid & 63;
    const int lg = l >> 4, lc = l & 15;
    const int q0 = blockIdx.x << 6;        // 64-row q-tile
    const int h = blockIdx.y, b = blockIdx.z;
    const int nk = slen[b];

    if ((q0 & ~127) >= nk) return;         // parent 128-tile skipped by gemm_o

    if (q0 >= nk) {
        // parent tile live but this half fully masked: write zeros so gemm_o
        // never reads stale Q rows.
#pragma unroll
        for (int rr = 0; rr < 4; ++rr) {
            int q = q0 + (w << 4) + (lg << 2) + rr;
            size_t base = (size_t)(b * Lsz + q) * Dsz + h * Dh + lc;
#pragma unroll
            for (int fd = 0; fd < 8; ++fd) {
                Ohi[base + fd * 16] = 0;
                Olo[base + fd * 16] = 0;
            }
        }
        return;
    }

    // ---- Q strip -> A-frags (pre-split bf16), once per block ----
    bf16x8 qh[4], ql[4];
    {
        size_t base = (size_t)(b * Lsz + q0 + (w << 4) + lc) * Dsz + h * Dh + lg * 8;
#pragma unroll
        for (int s = 0; s < 4; ++s) {
            qh[s] = *(const bf16x8*)&Qhi[base + s * 32];
            ql[s] = *(const bf16x8*)&Qlo[base + s * 32];
        }
    }

    // ---- staging decode (256 threads, 1024 chunks each of K and Vt) ----
    const ushort* ksrc[4]; int klds[4];
    const ushort* vsrc[4]; int vlds[4];
#pragma unroll
    for (int i = 0; i < 4; ++i) {
        int s = i * 256 + tid;              // K chunk: row j (32ch: 16 hi + 16 lo)
        int j = s >> 5, p = s & 31;
        int lg4 = (p & 15) ^ (j & 15);
        const ushort* base = (p & 16) ? Klo : Khi;
        ksrc[i] = base + (size_t)(b * Lsz + j) * Dsz + h * Dh + lg4 * 8;
        klds[i] = s * 8;
    }
#pragma unroll
    for (int i = 0; i < 4; ++i) {
        int s = i * 256 + tid;              // Vt chunk: row d (8ch: 4 hi + 4 lo)
        int d = s >> 3, p = s & 7;
        int lgc = p ^ (d & 7);
        const ushort* base = (lgc & 4) ? Vtlo : Vthi;
        vsrc[i] = base + (size_t)(h * Dh + d) * (Bsz * Lsz) + b * Lsz + (lgc & 3) * 8;
        vlds[i] = s * 8;
    }

    f32x4 oacc[8];
#pragma unroll
    for (int fd = 0; fd < 8; ++fd) oacc[fd] = (f32x4)0.f;
    float lsum[4] = {0.f, 0.f, 0.f, 0.f};
    const int pbase = w * (16 * 36);

    for (int kb = 0; kb < nk; kb += 32) {
        // ---- stage K + V^T tiles ----
#pragma unroll
        for (int i = 0; i < 4; ++i) gload16(ksrc[i] + (size_t)kb * Dsz, &Ks[klds[i]]);
#pragma unroll
        for (int i = 0; i < 4; ++i) gload16(vsrc[i] + kb, &Vs[vlds[i]]);
        __syncthreads();

        // ---- S = Q K^T (16x32 per wave) ----
        f32x4 sa[2] = {(f32x4)0.f, (f32x4)0.f};
        __builtin_amdgcn_s_setprio(1);
#pragma unroll
        for (int fn = 0; fn < 2; ++fn) {
            int j = fn * 16 + lc;
            int ro = j * 256;
#pragma unroll
            for (int s = 0; s < 4; ++s) {
                int phys = (s * 4 + lg) ^ (j & 15);
                bf16x8 kh = *(const bf16x8*)&Ks[ro + phys * 8];
                bf16x8 kl = *(const bf16x8*)&Ks[ro + 128 + phys * 8];
                sa[fn] = __builtin_amdgcn_mfma_f32_16x16x32_bf16(qh[s], kh, sa[fn], 0, 0, 0);
                sa[fn] = __builtin_amdgcn_mfma_f32_16x16x32_bf16(qh[s], kl, sa[fn], 0, 0, 0);
                sa[fn] = __builtin_amdgcn_mfma_f32_16x16x32_bf16(ql[s], kh, sa[fn], 0, 0, 0);
            }
        }
        __builtin_amdgcn_s_setprio(0);

        // ---- mask tail keys (last tile only; wave-uniform branch) ----
        if (kb + 32 > nk) {
#pragma unroll
            for (int fn = 0; fn < 2; ++fn) {
                bool oob = (kb + fn * 16 + lc) >= nk;
#pragma unroll
                for (int rr = 0; rr < 4; ++rr)
                    sa[fn][rr] = oob ? -1e30f : sa[fn][rr];
            }
        }

        // ---- exp (max-free), accumulate row sums, split+pack P to LDS ----
#pragma unroll
        for (int fn = 0; fn < 2; ++fn)
#pragma unroll
            for (int rr = 0; rr < 4; ++rr) {
                float p = __expf(sa[fn][rr]);
                lsum[rr] += p;
                unsigned int u = __float_as_uint(p);
                float res = p - __uint_as_float(u & 0xffff0000u);
                unsigned int lo16 = __float_as_uint(res) >> 16;
                Pb[pbase + (lg * 4 + rr) * 36 + fn * 16 + lc] =
                    (lo16 << 16) | (u >> 16);
            }

        // ---- P: LDS -> A-frags (per-wave region; no barrier needed) ----
        const unsigned int* pr = &Pb[pbase + lc * 36 + lg * 8];
        uint4 a0 = *(const uint4*)pr;
        uint4 a1 = *(const uint4*)(pr + 4);
        FragU PH, PL;
        PH.u[0] = (a0.x & 0xffffu) | (a0.y << 16);
        PH.u[1] = (a0.z & 0xffffu) | (a0.w << 16);
        PH.u[2] = (a1.x & 0xffffu) | (a1.y << 16);
        PH.u[3] = (a1.z & 0xffffu) | (a1.w << 16);
        PL.u[0] = (a0.x >> 16) | (a0.y & 0xffff0000u);
        PL.u[1] = (a0.z >> 16) | (a0.w & 0xffff0000u);
        PL.u[2] = (a1.x >> 16) | (a1.y & 0xffff0000u);
        PL.u[3] = (a1.z >> 16) | (a1.w & 0xffff0000u);

        // ---- O += P V (16x128 per wave) ----
        __builtin_amdgcn_s_setprio(1);
#pragma unroll
        for (int fd = 0; fd < 8; ++fd) {
            int d = fd * 16 + lc;
            int ro = d * 64;
            int ph = lg ^ (d & 7);
            int pl2 = (4 + lg) ^ (d & 7);
            bf16x8 vh = *(const bf16x8*)&Vs[ro + ph * 8];
            bf16x8 vl = *(const bf16x8*)&Vs[ro + pl2 * 8];
            oacc[fd] = __builtin_amdgcn_mfma_f32_16x16x32_bf16(PH.f, vh, oacc[fd], 0, 0, 0);
            oacc[fd] = __builtin_amdgcn_mfma_f32_16x16x32_bf16(PH.f, vl, oacc[fd], 0, 0, 0);
            oacc[fd] = __builtin_amdgcn_mfma_f32_16x16x32_bf16(PL.f, vh, oacc[fd], 0, 0, 0);
        }
        __builtin_amdgcn_s_setprio(0);
        __syncthreads();   // protect Ks/Vs before next stage
    }

    // ---- reduce row sums across the 16 lanes of each quad group ----
#pragma unroll
    for (int m = 1; m < 16; m <<= 1)
#pragma unroll
        for (int rr = 0; rr < 4; ++rr)
            lsum[rr] += __shfl_xor(lsum[rr], m, 64);

    // ---- normalize, query-mask, split, store (in-place over Qhi/Qlo) ----
#pragma unroll
    for (int rr = 0; rr < 4; ++rr) {
        int q = q0 + (w << 4) + (lg << 2) + rr;
        bool valid = q < nk;
        float inv = valid ? (1.f / lsum[rr]) : 0.f;
        size_t base = (size_t)(b * Lsz + q) * Dsz + h * Dh + lc;
#pragma unroll
        for (int fd = 0; fd < 8; ++fd) {
            float val = valid ? oacc[fd][rr] * inv : 0.f;
            unsigned int u = __float_as_uint(val);
            float res = val - __uint_as_float(u & 0xffff0000u);
            Ohi[base + fd * 16] = (unsigned short)(u >> 16);
            Olo[base + fd * 16] = (unsigned short)(__float_as_uint(res) >> 16);
        }
    }
}

// ---------------------------------------------------------------------------
// ws: Qhi|Qlo|Khi|Klo|Vthi|Vtlo (6 x MD ushort) + Wfh|Wfl (fused QKV weights,
// 2 x 3WD) + Woh|Wol (2 x WD) = 6 MD + 8 WD ushort = 117.4 MB (validated).
// 4 launches total: conv_w4, gemm_qkv, flash_mfma, gemm_o.
// ---------------------------------------------------------------------------
extern "C" void kernel_launch(void* const* d_in, const int* in_sizes, int n_in,
                              void* d_out, int out_size, void* d_ws, size_t ws_size,
                              hipStream_t stream) {
    (void)in_sizes; (void)n_in; (void)out_size; (void)ws_size;
    const float* queries = (const float*)d_in[0];
    const float* keys    = (const float*)d_in[1];
    const int*   slen    = (const int*)d_in[2];
    const float* Wq      = (const float*)d_in[3];
    const float* Wk      = (const float*)d_in[4];
    const float* Wv      = (const float*)d_in[5];
    const float* Wo      = (const float*)d_in[6];
    float* out = (float*)d_out;

    const size_t MD = (size_t)Bsz * Lsz * Dsz;   // 8388608
    const size_t WD = (size_t)Dsz * Dsz;         // 1048576
    ushort* Qhi  = (ushort*)d_ws;
    ushort* Qlo  = Qhi + MD;
    ushort* Khi  = Qlo + MD;
    ushort* Klo  = Khi + MD;
    ushort* Vthi = Klo + MD;
    ushort* Vtlo = Vthi + MD;
    ushort* Wfh  = Vtlo + MD;      // fused: rows [0,1024)=Wq*s, [1024,2048)=Wk, [2048,3072)=Wv
    ushort* Wfl  = Wfh + 3 * WD;
    ushort* Woh  = Wfl + 3 * WD;
    ushort* Wol  = Woh + WD;

    const float scaleQ = 0.08838834764831845f;   // 1/sqrt(Dh), folded into Wq
    WConv4 wa;
    wa.w[0] = (const float4*)Wq; wa.h[0] = (ushort4*)Wfh;            wa.l[0] = (ushort4*)Wfl;            wa.s[0] = scaleQ;
    wa.w[1] = (const float4*)Wk; wa.h[1] = (ushort4*)(Wfh + WD);     wa.l[1] = (ushort4*)(Wfl + WD);     wa.s[1] = 1.f;
    wa.w[2] = (const float4*)Wv; wa.h[2] = (ushort4*)(Wfh + 2 * WD); wa.l[2] = (ushort4*)(Wfl + 2 * WD); wa.s[2] = 1.f;
    wa.w[3] = (const float4*)Wo; wa.h[3] = (ushort4*)Woh;            wa.l[3] = (ushort4*)Wol;            wa.s[3] = 1.f;
    conv_w4<<<4096, 256, 0, stream>>>(wa);

    // fused Q+K+V projections: N = 3072, grid (24, 64), 512 threads
    gemm_qkv<<<dim3(24, 64), 512, 0, stream>>>(
        queries, keys, Wfh, Wfl, Qhi, Qlo, Khi, Klo, Vthi, Vtlo, slen);

    // flash attention: 64-row q-tiles, 256 threads (4 waves)
    dim3 ga(Lsz / 64, Hn, Bsz);        // (32, 8, 4)
    flash_mfma<<<ga, 256, 0, stream>>>(Qhi, Qlo, Khi, Klo, Vthi, Vtlo, slen,
                                       Qhi, Qlo /* O in-place */);

    // output projection (reads pre-split O; masked tiles -> zeros)
    gemm_o<<<dim3(8, 64), 512, 0, stream>>>(Qhi, Qlo, Woh, Wol, out, slen);
}